// Round 7
// baseline (2056.498 us; speedup 1.0000x reference)
//
#include <hip/hip_runtime.h>

// Problem constants (from reference): 16 clouds x 4096 pts, sample 1024, D=512
#define N_PER   4096
#define M_SAMP  1024
#define B_CL    16
#define D_FEAT  512
#define TPB     256
#define NWAVE   (TPB / 64)      // 4 waves
#define PPT     (N_PER / TPB)   // 16 points per thread
#define NPAIR   (PPT / 2)       // 8 packed pairs per thread
#define CPW     2               // clouds per workgroup (interleaved chains)

typedef float v2f __attribute__((ext_vector_type(2)));

// ---------------------------------------------------------------------------
// DPP 5-tuple argmax combine: u64 key desc + winner coords (x,y,z).
// key = (float_bits(val) << 32) | (4095 - idx):
//   max key == max val; tie -> min idx  (exact jnp.argmax first-occurrence).
// Lanes not supplied by the DPP pattern combine with themselves (no-op).
// ---------------------------------------------------------------------------
template <int CTRL>
__device__ __forceinline__ void dpp_combine5(unsigned& khi, unsigned& klo,
                                             float& x, float& y, float& z) {
    unsigned h2 = (unsigned)__builtin_amdgcn_update_dpp((int)khi, (int)khi, CTRL, 0xF, 0xF, false);
    unsigned l2 = (unsigned)__builtin_amdgcn_update_dpp((int)klo, (int)klo, CTRL, 0xF, 0xF, false);
    int xi = __builtin_amdgcn_update_dpp(__float_as_int(x), __float_as_int(x), CTRL, 0xF, 0xF, false);
    int yi = __builtin_amdgcn_update_dpp(__float_as_int(y), __float_as_int(y), CTRL, 0xF, 0xF, false);
    int zi = __builtin_amdgcn_update_dpp(__float_as_int(z), __float_as_int(z), CTRL, 0xF, 0xF, false);
    unsigned long long k  = ((unsigned long long)khi << 32) | klo;
    unsigned long long k2 = ((unsigned long long)h2  << 32) | l2;
    if (k2 > k) {
        khi = h2; klo = l2;
        x = __int_as_float(xi); y = __int_as_float(yi); z = __int_as_float(zi);
    }
}

// Per-cloud step: dist update (packed f32, contract off = exact jnp rounding),
// per-thread argmax carrying coords (all static register indexing), then
// wave64 DPP reduce. Returns wave winner in (khi,klo,cx,cy,cz) at lane 63.
__device__ __forceinline__ void fps_step(const v2f (&px2)[NPAIR], const v2f (&py2)[NPAIR],
                                         const v2f (&pz2)[NPAIR], v2f (&dist2)[NPAIR],
                                         float lx, float ly, float lz, int base,
                                         unsigned& khi, unsigned& klo,
                                         float& cx, float& cy, float& cz) {
    float bv = -1.0f;                 // all dist >= 0, so always beaten
    int   bj = 0;
    float bx = px2[0].x, by = py2[0].x, bz = pz2[0].x;
    v2f lxv = {lx, lx}, lyv = {ly, ly}, lzv = {lz, lz};
#pragma unroll
    for (int p = 0; p < NPAIR; ++p) {
#pragma clang fp contract(off)
        v2f dx = px2[p] - lxv;
        v2f dy = py2[p] - lyv;
        v2f dz = pz2[p] - lzv;
        v2f d2 = dx * dx + dy * dy + dz * dz;      // pk_mul + pk_add, no fma
        v2f dn = __builtin_elementwise_min(dist2[p], d2);
        dist2[p] = dn;
        // ascending index + strict '>' => first occurrence
        bool t0 = dn.x > bv;
        bv = t0 ? dn.x : bv; bj = t0 ? 2 * p : bj;
        bx = t0 ? px2[p].x : bx; by = t0 ? py2[p].x : by; bz = t0 ? pz2[p].x : bz;
        bool t1 = dn.y > bv;
        bv = t1 ? dn.y : bv; bj = t1 ? 2 * p + 1 : bj;
        bx = t1 ? px2[p].y : bx; by = t1 ? py2[p].y : by; bz = t1 ? pz2[p].y : bz;
    }
    khi = __float_as_uint(bv);                  // bv >= 0: bits monotone
    klo = (unsigned)(N_PER - 1 - (base + bj));  // tie -> smaller idx wins
    cx = bx; cy = by; cz = bz;
    dpp_combine5<0xB1>(khi, klo, cx, cy, cz);   // quad_perm xor1
    dpp_combine5<0x4E>(khi, klo, cx, cy, cz);   // quad_perm xor2
    dpp_combine5<0x141>(khi, klo, cx, cy, cz);  // row_half_mirror
    dpp_combine5<0x140>(khi, klo, cx, cy, cz);  // row_mirror
    dpp_combine5<0x142>(khi, klo, cx, cy, cz);  // row_bcast15
    dpp_combine5<0x143>(khi, klo, cx, cy, cz);  // row_bcast31
}

// ---------------------------------------------------------------------------
// FPS: TWO independent clouds per workgroup, steps interleaved so one cloud's
// dist/reduce issue hides the other's barrier + merge-read latency. 8 blocks.
// waves_per_eu(1,1): 8 blocks chip-wide, occupancy worthless; full VGPR budget
// keeps both clouds' arrays in real VGPRs (no AGPR shuttles -- R6 lesson).
// Winner coords ride the reduction and the merge slots: zero dependent coord
// lookup, tiny LDS, no bank conflicts.
// ---------------------------------------------------------------------------
__global__ __launch_bounds__(TPB)
__attribute__((amdgpu_waves_per_eu(1, 1)))
void fps_kernel(const float* __restrict__ pos, int* __restrict__ sidx) {
    __shared__ uint4 sw4[CPW][2][NWAVE];   // [cloud][buf][wave] = {khi,klo,x,y}
    __shared__ float swz[CPW][2][NWAVE];   // z
    __shared__ int   sloc[CPW][M_SAMP];    // sampled local indices (8 KiB)

    const int tid    = threadIdx.x;
    const int cloudA = blockIdx.x * CPW;
    const int cloudB = cloudA + 1;
    const float* posA = pos + (size_t)cloudA * N_PER * 3;
    const float* posB = pos + (size_t)cloudB * N_PER * 3;
    const int base = tid * PPT;

    // preload both clouds' points (12 aligned float4 each) into packed regs
    v2f pxA[NPAIR], pyA[NPAIR], pzA[NPAIR], dA[NPAIR];
    v2f pxB[NPAIR], pyB[NPAIR], pzB[NPAIR], dB[NPAIR];
    {
        float f[48];
        const float4* p4 = (const float4*)posA + tid * 12;
#pragma unroll
        for (int v = 0; v < 12; ++v) {
            float4 t = p4[v];
            f[4 * v] = t.x; f[4 * v + 1] = t.y; f[4 * v + 2] = t.z; f[4 * v + 3] = t.w;
        }
#pragma unroll
        for (int p = 0; p < NPAIR; ++p) {
            pxA[p] = (v2f){f[6 * p], f[6 * p + 3]};
            pyA[p] = (v2f){f[6 * p + 1], f[6 * p + 4]};
            pzA[p] = (v2f){f[6 * p + 2], f[6 * p + 5]};
            dA[p] = (v2f){1e30f, 1e30f};
        }
        p4 = (const float4*)posB + tid * 12;
#pragma unroll
        for (int v = 0; v < 12; ++v) {
            float4 t = p4[v];
            f[4 * v] = t.x; f[4 * v + 1] = t.y; f[4 * v + 2] = t.z; f[4 * v + 3] = t.w;
        }
#pragma unroll
        for (int p = 0; p < NPAIR; ++p) {
            pxB[p] = (v2f){f[6 * p], f[6 * p + 3]};
            pyB[p] = (v2f){f[6 * p + 1], f[6 * p + 4]};
            pzB[p] = (v2f){f[6 * p + 2], f[6 * p + 5]};
            dB[p] = (v2f){1e30f, 1e30f};
        }
    }

    float lxA = posA[0], lyA = posA[1], lzA = posA[2];   // start = local 0
    float lxB = posB[0], lyB = posB[1], lzB = posB[2];
    if (tid == 0) { sloc[0][0] = 0; sloc[1][0] = 0; }

    const int wave = tid >> 6;
    const int lane = tid & 63;

    for (int s = 1; s < M_SAMP; ++s) {
        const int buf = s & 1;
        // ---- cloud A: dist + wave reduce, post winner ----
        {
            unsigned khi, klo; float cx, cy, cz;
            fps_step(pxA, pyA, pzA, dA, lxA, lyA, lzA, base, khi, klo, cx, cy, cz);
            if (lane == 63) {
                sw4[0][buf][wave] = make_uint4(khi, klo, __float_as_uint(cx), __float_as_uint(cy));
                swz[0][buf][wave] = cz;
            }
        }
        // ---- cloud B: same (issues while A's DS writes are in flight) ----
        {
            unsigned khi, klo; float cx, cy, cz;
            fps_step(pxB, pyB, pzB, dB, lxB, lyB, lzB, base, khi, klo, cx, cy, cz);
            if (lane == 63) {
                sw4[1][buf][wave] = make_uint4(khi, klo, __float_as_uint(cx), __float_as_uint(cy));
                swz[1][buf][wave] = cz;
            }
        }
        __syncthreads();   // one barrier drains both clouds' slot writes

        // ---- merge A and B (independent broadcast reads, one latency window)
        {
            uint4 m = sw4[0][buf][0]; float mz = swz[0][buf][0];
#pragma unroll
            for (int w = 1; w < NWAVE; ++w) {
                uint4 t = sw4[0][buf][w]; float tz = swz[0][buf][w];
                unsigned long long k  = ((unsigned long long)m.x << 32) | m.y;
                unsigned long long k2 = ((unsigned long long)t.x << 32) | t.y;
                if (k2 > k) { m = t; mz = tz; }
            }
            lxA = __uint_as_float(m.z); lyA = __uint_as_float(m.w); lzA = mz;
            if (tid == 0) sloc[0][s] = N_PER - 1 - (int)m.y;
        }
        {
            uint4 m = sw4[1][buf][0]; float mz = swz[1][buf][0];
#pragma unroll
            for (int w = 1; w < NWAVE; ++w) {
                uint4 t = sw4[1][buf][w]; float tz = swz[1][buf][w];
                unsigned long long k  = ((unsigned long long)m.x << 32) | m.y;
                unsigned long long k2 = ((unsigned long long)t.x << 32) | t.y;
                if (k2 > k) { m = t; mz = tz; }
            }
            lxB = __uint_as_float(m.z); lyB = __uint_as_float(m.w); lzB = mz;
            if (tid == 0) sloc[1][s] = N_PER - 1 - (int)m.y;
        }
    }

    // dump both clouds' sampled indices to global once (coalesced)
    __syncthreads();
    for (int i = tid; i < M_SAMP; i += TPB) {
        sidx[cloudA * M_SAMP + i] = sloc[0][i];
        sidx[cloudB * M_SAMP + i] = sloc[1][i];
    }
}

// ---------------------------------------------------------------------------
// Fused gather: blocks [0,8192) copy x rows (float4-vectorized, 16384 rows x
// 128 f4); blocks [8192, 8256) handle pos (3 f32/row) + batch (as float).
// sidx holds LOCAL per-cloud indices; globalize with (r/1024)*4096.
// ---------------------------------------------------------------------------
__global__ __launch_bounds__(256) void gather_kernel(const float4* __restrict__ x4,
                                                     const float* __restrict__ pos,
                                                     const int* __restrict__ batch,
                                                     const int* __restrict__ sidx,
                                                     float4* __restrict__ out4,
                                                     float* __restrict__ out_pos,
                                                     float* __restrict__ out_batch) {
    int b = blockIdx.x;
    if (b < 8192) {
        int id = b * 256 + threadIdx.x;          // 0 .. 16384*128-1
        int r  = id >> 7;                        // output row
        int c  = id & 127;                       // float4 column
        int g  = sidx[r] + (r >> 10 << 12);      // + (r/1024)*4096
        out4[id] = x4[(size_t)g * (D_FEAT / 4) + c];
    } else {
        int r = (b - 8192) * 256 + threadIdx.x;  // 0 .. 16383
        int g = sidx[r] + (r >> 10 << 12);
        out_pos[r * 3 + 0] = pos[g * 3 + 0];
        out_pos[r * 3 + 1] = pos[g * 3 + 1];
        out_pos[r * 3 + 2] = pos[g * 3 + 2];
        out_batch[r] = (float)batch[g];
    }
}

extern "C" void kernel_launch(void* const* d_in, const int* in_sizes, int n_in,
                              void* d_out, int out_size, void* d_ws, size_t ws_size,
                              hipStream_t stream) {
    const float* x     = (const float*)d_in[0];   // [65536,512] f32
    const float* pos   = (const float*)d_in[1];   // [65536,3]   f32
    const int*   batch = (const int*)d_in[2];     // [65536]     i32

    int* sidx = (int*)d_ws;                       // [16384] local sampled indices

    float* out   = (float*)d_out;
    float* out_x = out;                                            // 16384*512
    float* out_p = out + (size_t)B_CL * M_SAMP * D_FEAT;           // 16384*3
    float* out_b = out_p + (size_t)B_CL * M_SAMP * 3;              // 16384

    // 1) FPS: 8 blocks, 2 clouds each, 256 threads
    fps_kernel<<<B_CL / CPW, TPB, 0, stream>>>(pos, sidx);

    // 2) fused gather: 8192 x-blocks + 64 pos/batch-blocks
    gather_kernel<<<8192 + 64, 256, 0, stream>>>(
        (const float4*)x, pos, batch, sidx, (float4*)out_x, out_p, out_b);
}